// Round 1
// baseline (912.062 us; speedup 1.0000x reference)
//
#include <hip/hip_runtime.h>
#include <hip/hip_bf16.h>

// CorotationalBeam2D: per-element 2D corotational beam forces + nodal scatter.
//
// Outputs (flat, concatenated in reference return order):
//   [0]              nodal_forces_nd : (N_NODES,3)
//   [3N]             F_ext_nd        : (N_NODES,3)
//   [6N]             N_e             : (N_ELEMS,)
//   [6N+E]           M1_e            : (N_ELEMS,)
//   [6N+2E]          M2_e            : (N_ELEMS,)
//   [6N+3E]          V_e             : (N_ELEMS,)
//   [6N+4E]          phys_disp       : (N_NODES,3)
//   [9N+4E]          l0              : (N_ELEMS,)
//   [9N+5E]          c               : (N_ELEMS,)
//   [9N+6E]          s               : (N_ELEMS,)

#ifndef __HIP_DEVICE_COMPILE__
#endif

__device__ __forceinline__ void atomic_add_f32(float* p, float v) {
#if defined(__gfx90a__) || defined(__gfx940__) || defined(__gfx941__) || defined(__gfx942__) || defined(__gfx950__)
    unsafeAtomicAdd(p, v);   // hardware global_atomic_add_f32
#else
    atomicAdd(p, v);
#endif
}

// Kernel 1: node-wise. phys_disp, F_ext_nd, and zero the nodal accumulator.
__global__ void beam_node_kernel(const float* __restrict__ pred,
                                 const float* __restrict__ Fext,
                                 const float* __restrict__ u_c_p,
                                 const float* __restrict__ theta_c_p,
                                 const float* __restrict__ F_c_p,
                                 const float* __restrict__ M_c_p,
                                 float* __restrict__ nodal,
                                 float* __restrict__ Fext_nd,
                                 float* __restrict__ phys,
                                 int n3) {
    int i = blockIdx.x * blockDim.x + threadIdx.x;
    if (i >= n3) return;
    const float u_c = *u_c_p;
    const float theta_c = *theta_c_p;
    const float F_c = *F_c_p;
    const float M_c = *M_c_p;
    int comp = i % 3;
    float dscale = (comp == 2) ? theta_c : u_c;
    float fscale = (comp == 2) ? M_c : F_c;
    phys[i]    = pred[i] * dscale;
    Fext_nd[i] = Fext[i] / fscale;
    nodal[i]   = 0.0f;
}

// Kernel 2: element-wise. Beam math + element outputs + atomic scatter.
__global__ void beam_elem_kernel(const float* __restrict__ pred,
                                 const float* __restrict__ coords,
                                 const int*   __restrict__ conn,
                                 const float* __restrict__ prop_E,
                                 const float* __restrict__ prop_A,
                                 const float* __restrict__ prop_I,
                                 const float* __restrict__ u_c_p,
                                 const float* __restrict__ theta_c_p,
                                 const float* __restrict__ F_c_p,
                                 const float* __restrict__ M_c_p,
                                 float* __restrict__ nodal,
                                 float* __restrict__ N_e,
                                 float* __restrict__ M1_e,
                                 float* __restrict__ M2_e,
                                 float* __restrict__ V_e,
                                 float* __restrict__ l0_o,
                                 float* __restrict__ c_o,
                                 float* __restrict__ s_o,
                                 int n_elems) {
    int e = blockIdx.x * blockDim.x + threadIdx.x;
    if (e >= n_elems) return;

    const float u_c = *u_c_p;
    const float theta_c = *theta_c_p;
    const float F_c = *F_c_p;
    const float M_c = *M_c_p;

    int nA = conn[2 * e + 0];
    int nB = conn[2 * e + 1];

    // geometry (x-z plane)
    float ax = coords[3 * nA + 0];
    float az = coords[3 * nA + 2];
    float bx = coords[3 * nB + 0];
    float bz = coords[3 * nB + 2];
    float dx0 = bx - ax;
    float dz0 = bz - az;
    float l0 = sqrtf(dx0 * dx0 + dz0 * dz0);
    float c = dx0 / l0;
    float s = dz0 / l0;

    float E = prop_E[e];
    float EA = E * prop_A[e];
    float EI = E * prop_I[e];

    float l0_2 = l0 * l0;
    float l0_3 = l0_2 * l0;
    float k_ax   = EA * u_c     / (F_c * l0);
    float k_bend = EI * theta_c / (M_c * l0);
    float k_sw   = EI * theta_c / (F_c * l0_2);
    float k_tr   = EI * u_c     / (F_c * l0_3);
    float k_mw   = EI * u_c     / (M_c * l0_2);

    float pA0 = pred[3 * nA + 0];
    float pA1 = pred[3 * nA + 1];
    float pA2 = pred[3 * nA + 2];
    float pB0 = pred[3 * nB + 0];
    float pB1 = pred[3 * nB + 1];
    float pB2 = pred[3 * nB + 2];

    float ua =  c * pA0 + s * pA1;
    float wa = -s * pA0 + c * pA1;
    float ta = -pA2;
    float ub =  c * pB0 + s * pB1;
    float wb = -s * pB0 + c * pB1;
    float tb = -pB2;

    float f0 = k_ax * (ua - ub);
    float f3 = k_ax * (ub - ua);
    float f1 = 12.0f * k_tr * (wa - wb) + 6.0f * k_sw * (ta + tb);
    float f4 = 12.0f * k_tr * (wb - wa) - 6.0f * k_sw * (ta + tb);
    float f2 = 6.0f * k_mw * (wa - wb) + k_bend * (4.0f * ta + 2.0f * tb);
    float f5 = 6.0f * k_mw * (wa - wb) + k_bend * (2.0f * ta + 4.0f * tb);

    // element outputs (coalesced)
    N_e[e]  = f3 * F_c;
    M1_e[e] = f2 * M_c;
    M2_e[e] = f5 * M_c;
    V_e[e]  = f4 * F_c;
    l0_o[e] = l0;
    c_o[e]  = c;
    s_o[e]  = s;

    // nodal scatter
    float fgA0 = c * f0 - s * f1;
    float fgA1 = s * f0 + c * f1;
    float fgB0 = c * f3 - s * f4;
    float fgB1 = s * f3 + c * f4;

    atomic_add_f32(&nodal[3 * nA + 0], fgA0);
    atomic_add_f32(&nodal[3 * nA + 1], fgA1);
    atomic_add_f32(&nodal[3 * nA + 2], f2);
    atomic_add_f32(&nodal[3 * nB + 0], fgB0);
    atomic_add_f32(&nodal[3 * nB + 1], fgB1);
    atomic_add_f32(&nodal[3 * nB + 2], f5);
}

extern "C" void kernel_launch(void* const* d_in, const int* in_sizes, int n_in,
                              void* d_out, int out_size, void* d_ws, size_t ws_size,
                              hipStream_t stream) {
    const float* pred    = (const float*)d_in[0];
    const float* coords  = (const float*)d_in[1];
    const int*   conn    = (const int*)  d_in[2];
    const float* prop_E  = (const float*)d_in[3];
    const float* prop_A  = (const float*)d_in[4];
    const float* prop_I  = (const float*)d_in[5];
    const float* Fext    = (const float*)d_in[6];
    const float* u_c_p   = (const float*)d_in[7];
    const float* th_c_p  = (const float*)d_in[8];
    const float* F_c_p   = (const float*)d_in[9];
    const float* M_c_p   = (const float*)d_in[10];

    const int n3      = in_sizes[0];        // N_NODES*3
    const int n_elems = in_sizes[3];        // N_ELEMS

    float* out     = (float*)d_out;
    float* nodal   = out;
    float* Fext_nd = nodal + (size_t)n3;
    float* N_e     = Fext_nd + (size_t)n3;
    float* M1_e    = N_e + (size_t)n_elems;
    float* M2_e    = M1_e + (size_t)n_elems;
    float* V_e     = M2_e + (size_t)n_elems;
    float* phys    = V_e + (size_t)n_elems;
    float* l0_o    = phys + (size_t)n3;
    float* c_o     = l0_o + (size_t)n_elems;
    float* s_o     = c_o + (size_t)n_elems;

    const int BLK = 256;
    int grid1 = (n3 + BLK - 1) / BLK;
    beam_node_kernel<<<grid1, BLK, 0, stream>>>(pred, Fext, u_c_p, th_c_p, F_c_p, M_c_p,
                                                nodal, Fext_nd, phys, n3);

    int grid2 = (n_elems + BLK - 1) / BLK;
    beam_elem_kernel<<<grid2, BLK, 0, stream>>>(pred, coords, conn, prop_E, prop_A, prop_I,
                                                u_c_p, th_c_p, F_c_p, M_c_p,
                                                nodal, N_e, M1_e, M2_e, V_e, l0_o, c_o, s_o,
                                                n_elems);
}